// Round 1
// baseline (1488.988 us; speedup 1.0000x reference)
//
#include <hip/hip_runtime.h>
#include <hip/hip_bf16.h>
#include <math.h>

// EnhancedSparseMoE: B=2,S=1024 -> T=2048 tokens, H=2048, I=1408, E=8, top-2.
// Round 1: correct fp32 sparse baseline.
//  k1: gating (fp32 exact: selection must match ref) + atomic bucketing
//  k2: grouped GEMM1 per expert -> act = silu(g)*u   (act in ws, ~23 MB)
//  k3: grouped GEMM2 per expert -> atomicAdd(w * act.W2^T) into zeroed out
#define T_TOK 2048
#define H_DIM 2048
#define I_DIM 1408
#define E_NUM 8

__global__ void moe_gating(const float* __restrict__ x, const float* __restrict__ gw,
                           float* __restrict__ wts, int* __restrict__ counts,
                           int* __restrict__ entries) {
    const int lane = threadIdx.x & 63;
    const int wv   = threadIdx.x >> 6;
    const int t    = blockIdx.x * 4 + wv;   // grid = T/4 blocks of 256
    float acc[E_NUM];
#pragma unroll
    for (int e = 0; e < E_NUM; ++e) acc[e] = 0.f;
    const float4* xr = (const float4*)(x + (size_t)t * H_DIM);
#pragma unroll
    for (int j = 0; j < 8; ++j) {           // 64 lanes * 4 floats * 8 = 2048
        float4 xv = xr[lane + 64 * j];
#pragma unroll
        for (int e = 0; e < E_NUM; ++e) {
            float4 g = ((const float4*)(gw + (size_t)e * H_DIM))[lane + 64 * j];
            acc[e] += xv.x * g.x + xv.y * g.y + xv.z * g.z + xv.w * g.w;
        }
    }
#pragma unroll
    for (int off = 32; off > 0; off >>= 1)
#pragma unroll
        for (int e = 0; e < E_NUM; ++e) acc[e] += __shfl_xor(acc[e], off, 64);

    if (lane == 0) {
        int a = 0; float la = acc[0];
        for (int e = 1; e < E_NUM; ++e) if (acc[e] > la) { la = acc[e]; a = e; }
        int b = (a == 0) ? 1 : 0; float lb = acc[b];
        for (int e = 0; e < E_NUM; ++e)
            if (e != a && acc[e] > lb) { lb = acc[e]; b = e; }
        // renormalized top-2 softmax weights: full-softmax denominator cancels
        float wa = 1.f / (1.f + expf(lb - la));
        wts[t * 2 + 0] = wa;
        wts[t * 2 + 1] = 1.f - wa;
        int p0 = atomicAdd(&counts[a], 1); entries[a * T_TOK + p0] = t * 2;
        int p1 = atomicAdd(&counts[b], 1); entries[b * T_TOK + p1] = t * 2 + 1;
    }
}

// act[v][0:I] = silu(x[t].W1g[i]) * (x[t].W1u[i]),  v = t*2+k (absolute row id)
__global__ __launch_bounds__(256)
void moe_gemm1(const float* __restrict__ x, const float* __restrict__ w1,
               const int* __restrict__ counts, const int* __restrict__ entries,
               float* __restrict__ act) {
    const int e  = blockIdx.z;
    const int ne = counts[e];
    const int tm = blockIdx.y;
    if (tm * 64 >= ne) return;
    const int tn = blockIdx.x;              // 0..21  (I/64)

    __shared__ float Xs[64][17];            // [m][kk]
    __shared__ float Gs[16][68];            // [kk][n]
    __shared__ float Us[16][68];
    __shared__ int   toks[64];

    const int tid = threadIdx.x;
    if (tid < 64) {
        int r = tm * 64 + tid;
        toks[tid] = (r < ne) ? entries[e * T_TOK + r] : -1;
    }
    __syncthreads();

    const int kk  = tid & 15;
    const int g16 = tid >> 4;               // 0..15
    const int tx  = tid & 15, ty = tid >> 4;
    const float* wgbase = w1 + ((size_t)e * 2 * I_DIM + (size_t)tn * 64) * H_DIM;
    const float* wubase = wgbase + (size_t)I_DIM * H_DIM;

    float accG[4][4], accU[4][4];
#pragma unroll
    for (int i = 0; i < 4; ++i)
#pragma unroll
        for (int j = 0; j < 4; ++j) { accG[i][j] = 0.f; accU[i][j] = 0.f; }

    for (int k0 = 0; k0 < H_DIM; k0 += 16) {
#pragma unroll
        for (int j = 0; j < 4; ++j) {
            int m = g16 * 4 + j;
            int v = toks[m]; int tok = (v < 0) ? 0 : (v >> 1);
            Xs[m][kk] = x[(size_t)tok * H_DIM + k0 + kk];
            Gs[kk][m] = wgbase[(size_t)m * H_DIM + k0 + kk];
            Us[kk][m] = wubase[(size_t)m * H_DIM + k0 + kk];
        }
        __syncthreads();
#pragma unroll
        for (int p = 0; p < 16; ++p) {
            float4 bg = *(const float4*)&Gs[p][tx * 4];
            float4 bu = *(const float4*)&Us[p][tx * 4];
#pragma unroll
            for (int mi = 0; mi < 4; ++mi) {
                float xv = Xs[ty * 4 + mi][p];
                accG[mi][0] = fmaf(xv, bg.x, accG[mi][0]);
                accG[mi][1] = fmaf(xv, bg.y, accG[mi][1]);
                accG[mi][2] = fmaf(xv, bg.z, accG[mi][2]);
                accG[mi][3] = fmaf(xv, bg.w, accG[mi][3]);
                accU[mi][0] = fmaf(xv, bu.x, accU[mi][0]);
                accU[mi][1] = fmaf(xv, bu.y, accU[mi][1]);
                accU[mi][2] = fmaf(xv, bu.z, accU[mi][2]);
                accU[mi][3] = fmaf(xv, bu.w, accU[mi][3]);
            }
        }
        __syncthreads();
    }
#pragma unroll
    for (int mi = 0; mi < 4; ++mi) {
        int m = ty * 4 + mi; int v = toks[m];
        if (v < 0) continue;
        float4 o;
        float g0 = accG[mi][0], g1 = accG[mi][1], g2 = accG[mi][2], g3 = accG[mi][3];
        o.x = (g0 / (1.f + expf(-g0))) * accU[mi][0];
        o.y = (g1 / (1.f + expf(-g1))) * accU[mi][1];
        o.z = (g2 / (1.f + expf(-g2))) * accU[mi][2];
        o.w = (g3 / (1.f + expf(-g3))) * accU[mi][3];
        *(float4*)&act[(size_t)v * I_DIM + tn * 64 + tx * 4] = o;
    }
}

// out[t][h] += wts[v] * (act[v] . w2[e][h])
__global__ __launch_bounds__(256)
void moe_gemm2(const float* __restrict__ act, const float* __restrict__ w2,
               const int* __restrict__ counts, const int* __restrict__ entries,
               const float* __restrict__ wts, float* __restrict__ out) {
    const int e  = blockIdx.z;
    const int ne = counts[e];
    const int tm = blockIdx.y;
    if (tm * 64 >= ne) return;
    const int tn = blockIdx.x;              // 0..31  (H/64)

    __shared__ float As[64][17];            // [m][kk]
    __shared__ float Bs[16][68];            // [kk][n]
    __shared__ int   toks[64];

    const int tid = threadIdx.x;
    if (tid < 64) {
        int r = tm * 64 + tid;
        toks[tid] = (r < ne) ? entries[e * T_TOK + r] : -1;
    }
    __syncthreads();

    const int kk  = tid & 15;
    const int g16 = tid >> 4;
    const int tx  = tid & 15, ty = tid >> 4;
    const float* wb = w2 + ((size_t)e * H_DIM + (size_t)tn * 64) * I_DIM;

    float acc[4][4];
#pragma unroll
    for (int i = 0; i < 4; ++i)
#pragma unroll
        for (int j = 0; j < 4; ++j) acc[i][j] = 0.f;

    for (int k0 = 0; k0 < I_DIM; k0 += 16) {
#pragma unroll
        for (int j = 0; j < 4; ++j) {
            int m = g16 * 4 + j;
            int v = toks[m]; int va = (v < 0) ? 0 : v;
            As[m][kk] = act[(size_t)va * I_DIM + k0 + kk];
            Bs[kk][m] = wb[(size_t)m * I_DIM + k0 + kk];
        }
        __syncthreads();
#pragma unroll
        for (int p = 0; p < 16; ++p) {
            float4 bb = *(const float4*)&Bs[p][tx * 4];
#pragma unroll
            for (int mi = 0; mi < 4; ++mi) {
                float av = As[ty * 4 + mi][p];
                acc[mi][0] = fmaf(av, bb.x, acc[mi][0]);
                acc[mi][1] = fmaf(av, bb.y, acc[mi][1]);
                acc[mi][2] = fmaf(av, bb.z, acc[mi][2]);
                acc[mi][3] = fmaf(av, bb.w, acc[mi][3]);
            }
        }
        __syncthreads();
    }
#pragma unroll
    for (int mi = 0; mi < 4; ++mi) {
        int m = ty * 4 + mi; int v = toks[m];
        if (v < 0) continue;
        int tok = v >> 1;
        float w = wts[v];
        float* op = out + (size_t)tok * H_DIM + tn * 64 + tx * 4;
        atomicAdd(op + 0, w * acc[mi][0]);
        atomicAdd(op + 1, w * acc[mi][1]);
        atomicAdd(op + 2, w * acc[mi][2]);
        atomicAdd(op + 3, w * acc[mi][3]);
    }
}

extern "C" void kernel_launch(void* const* d_in, const int* in_sizes, int n_in,
                              void* d_out, int out_size, void* d_ws, size_t ws_size,
                              hipStream_t stream) {
    const float* x  = (const float*)d_in[0];   // [T, H]
    const float* gw = (const float*)d_in[1];   // [E, H]
    const float* w1 = (const float*)d_in[2];   // [E, 2I, H]
    const float* w2 = (const float*)d_in[3];   // [E, H, I]
    float* out = (float*)d_out;                // [T, H]

    char* ws = (char*)d_ws;
    int*   counts  = (int*)ws;                             // 32 B
    int*   entries = (int*)(ws + 256);                     // E*T*4 = 64 KiB
    float* wts     = (float*)(ws + 256 + 65536);           // 2T*4 = 16 KiB
    float* act     = (float*)(ws + 256 + 65536 + 16384);   // 2T*I*4 = 22 MiB

    hipMemsetAsync(counts, 0, E_NUM * sizeof(int), stream);
    hipMemsetAsync(d_out, 0, (size_t)T_TOK * H_DIM * sizeof(float), stream);

    moe_gating<<<T_TOK / 4, 256, 0, stream>>>(x, gw, wts, counts, entries);
    moe_gemm1<<<dim3(I_DIM / 64, 32, E_NUM), 256, 0, stream>>>(x, w1, counts, entries, act);
    moe_gemm2<<<dim3(H_DIM / 64, 32, E_NUM), 256, 0, stream>>>(act, w2, counts, entries, wts, out);
}

// Round 2
// 567.259 us; speedup vs baseline: 2.6249x; 2.6249x over previous
//
#include <hip/hip_runtime.h>
#include <hip/hip_bf16.h>
#include <math.h>

// EnhancedSparseMoE round 2: bf16 MFMA grouped GEMMs (m97-style), fp32 gating.
// T=2048 tokens, H=2048, I=1408, E=8, top-2.
#define T_TOK 2048
#define H_DIM 2048
#define I_DIM 1408
#define E_NUM 8
#define I2    2816   // 2*I

typedef __attribute__((ext_vector_type(8))) short short8;
typedef __attribute__((ext_vector_type(4))) float floatx4;
typedef __attribute__((ext_vector_type(8))) unsigned short ushort8;
typedef unsigned short u16;

__device__ __forceinline__ u16 f2bf(float x) {   // RNE, matches __float2bfloat16
    unsigned u = __builtin_bit_cast(unsigned, x);
    return (u16)((u + 0x7FFFu + ((u >> 16) & 1u)) >> 16);
}

__device__ __forceinline__ floatx4 mfma16(short8 a, short8 b, floatx4 c) {
    return __builtin_amdgcn_mfma_f32_16x16x32_bf16(a, b, c, 0, 0, 0);
}

__device__ __forceinline__ void gload16(const u16* g, u16* l) {
    __builtin_amdgcn_global_load_lds(
        (const __attribute__((address_space(1))) unsigned int*)g,
        (__attribute__((address_space(3))) unsigned int*)l, 16, 0, 0);
}

// chunk swizzle: row r, logical 16B-chunk c lives at phys chunk c ^ swz(r)
__device__ __forceinline__ int swz(int r) { return (r & 3) ^ ((r >> 2) & 3); }

// ---------------- gating (fp32 exact, unchanged from round 1) ----------------
__global__ void moe_gating(const float* __restrict__ x, const float* __restrict__ gw,
                           float* __restrict__ wts, int* __restrict__ counts,
                           int* __restrict__ entries) {
    const int lane = threadIdx.x & 63;
    const int wv   = threadIdx.x >> 6;
    const int t    = blockIdx.x * 4 + wv;
    float acc[E_NUM];
#pragma unroll
    for (int e = 0; e < E_NUM; ++e) acc[e] = 0.f;
    const float4* xr = (const float4*)(x + (size_t)t * H_DIM);
#pragma unroll
    for (int j = 0; j < 8; ++j) {
        float4 xv = xr[lane + 64 * j];
#pragma unroll
        for (int e = 0; e < E_NUM; ++e) {
            float4 g = ((const float4*)(gw + (size_t)e * H_DIM))[lane + 64 * j];
            acc[e] += xv.x * g.x + xv.y * g.y + xv.z * g.z + xv.w * g.w;
        }
    }
#pragma unroll
    for (int off = 32; off > 0; off >>= 1)
#pragma unroll
        for (int e = 0; e < E_NUM; ++e) acc[e] += __shfl_xor(acc[e], off, 64);

    if (lane == 0) {
        int a = 0; float la = acc[0];
        for (int e = 1; e < E_NUM; ++e) if (acc[e] > la) { la = acc[e]; a = e; }
        int b = (a == 0) ? 1 : 0; float lb = acc[b];
        for (int e = 0; e < E_NUM; ++e)
            if (e != a && acc[e] > lb) { lb = acc[e]; b = e; }
        float wa = 1.f / (1.f + expf(lb - la));
        wts[t * 2 + 0] = wa;
        wts[t * 2 + 1] = 1.f - wa;
        int p0 = atomicAdd(&counts[a], 1); entries[a * T_TOK + p0] = t * 2;
        int p1 = atomicAdd(&counts[b], 1); entries[b * T_TOK + p1] = t * 2 + 1;
    }
}

// ---------------- fp32 -> bf16 conversion ----------------
__global__ __launch_bounds__(256)
void cvt_bf16(const float* __restrict__ src, u16* __restrict__ dst, int n8) {
    int i = blockIdx.x * 256 + threadIdx.x;
    if (i >= n8) return;
    const float4* s4 = (const float4*)src;
    float4 a = s4[2 * i], b = s4[2 * i + 1];
    ushort8 o;
    o[0] = f2bf(a.x); o[1] = f2bf(a.y); o[2] = f2bf(a.z); o[3] = f2bf(a.w);
    o[4] = f2bf(b.x); o[5] = f2bf(b.y); o[6] = f2bf(b.z); o[7] = f2bf(b.w);
    *(ushort8*)(dst + (size_t)i * 8) = o;
}

// ---------------- gemm1: act[v] = silu(x.Wg^T) * (x.Wu^T), bf16 MFMA ----------------
// block tile: M=128 (gathered rows), N=64 o-range (both G and U); 4 waves, each 64x32.
template <bool BPRE>
__global__ __launch_bounds__(256)
void moe_mfma1(const u16* __restrict__ xb, const void* __restrict__ w1v,
               const int* __restrict__ counts, const int* __restrict__ entries,
               u16* __restrict__ act) {
    const int e  = blockIdx.z;
    const int ne = counts[e];
    const int tm = blockIdx.y;
    if (tm * 128 >= ne) return;
    const int tn = blockIdx.x;               // o-base = tn*64

    __shared__ __align__(16) u16 As[128 * 32];
    __shared__ __align__(16) u16 Bg[64 * 32];
    __shared__ __align__(16) u16 Bu[64 * 32];
    __shared__ int rowv[128];

    const int tid = threadIdx.x;
    if (tid < 128) {
        int r = tm * 128 + tid;
        rowv[tid] = (r < ne) ? entries[(size_t)e * T_TOK + r] : -1;
    }
    __syncthreads();

    // A staging: 2 rounds x 256 thr x 16B = 8 KB tile (128 rows x 32 k)
    const u16* asrc[2]; u16* adst[2];
#pragma unroll
    for (int q = 0; q < 2; ++q) {
        int i = q * 256 + tid;
        int row = i >> 2, p = i & 3;
        int lc = p ^ swz(row);
        int v = rowv[row];
        int tok = (v < 0) ? 0 : (v >> 1);
        asrc[q] = xb + (size_t)tok * H_DIM + lc * 8;
        adst[q] = As + i * 8;
    }
    // B staging: 1 round each for G and U (64 rows x 32 k = 4 KB)
    const int brow = tid >> 2, bp = tid & 3;
    const int blc  = bp ^ swz(brow);
    const u16*   w1b = (const u16*)w1v;
    const float* w1f = (const float*)w1v;
    const size_t grow = ((size_t)e * I2 + tn * 64 + brow) * H_DIM + blc * 8;
    const size_t urow = grow + (size_t)I_DIM * H_DIM;
    u16* bgdst = Bg + tid * 8;
    u16* budst = Bu + tid * 8;

    const int lane = tid & 63, wid = tid >> 6;
    const int wm = wid & 1, wn = wid >> 1;

    floatx4 accG[4][2], accU[4][2];
    const floatx4 z4 = {0.f, 0.f, 0.f, 0.f};
#pragma unroll
    for (int mi = 0; mi < 4; ++mi)
#pragma unroll
        for (int ni = 0; ni < 2; ++ni) { accG[mi][ni] = z4; accU[mi][ni] = z4; }

    int aoff[4], boff[2];
#pragma unroll
    for (int mi = 0; mi < 4; ++mi) {
        int m = wm * 64 + mi * 16 + (lane & 15);
        aoff[mi] = m * 32 + (((lane >> 4) ^ swz(m)) * 8);
    }
#pragma unroll
    for (int ni = 0; ni < 2; ++ni) {
        int n = wn * 32 + ni * 16 + (lane & 15);
        boff[ni] = n * 32 + (((lane >> 4) ^ swz(n)) * 8);
    }

    for (int k0 = 0; k0 < H_DIM; k0 += 32) {
        gload16(asrc[0] + k0, adst[0]);
        gload16(asrc[1] + k0, adst[1]);
        if (BPRE) {
            gload16(w1b + grow + k0, bgdst);
            gload16(w1b + urow + k0, budst);
        } else {
            const float* gs = w1f + grow + k0;
            const float* us = w1f + urow + k0;
            float4 g0 = *(const float4*)gs, g1 = *(const float4*)(gs + 4);
            float4 u0 = *(const float4*)us, u1 = *(const float4*)(us + 4);
            ushort8 gv, uv;
            gv[0] = f2bf(g0.x); gv[1] = f2bf(g0.y); gv[2] = f2bf(g0.z); gv[3] = f2bf(g0.w);
            gv[4] = f2bf(g1.x); gv[5] = f2bf(g1.y); gv[6] = f2bf(g1.z); gv[7] = f2bf(g1.w);
            uv[0] = f2bf(u0.x); uv[1] = f2bf(u0.y); uv[2] = f2bf(u0.z); uv[3] = f2bf(u0.w);
            uv[4] = f2bf(u1.x); uv[5] = f2bf(u1.y); uv[6] = f2bf(u1.z); uv[7] = f2bf(u1.w);
            *(ushort8*)bgdst = gv;
            *(ushort8*)budst = uv;
        }
        __syncthreads();
        short8 a[4], bg[2], bu[2];
#pragma unroll
        for (int mi = 0; mi < 4; ++mi) a[mi] = *(const short8*)(As + aoff[mi]);
#pragma unroll
        for (int ni = 0; ni < 2; ++ni) {
            bg[ni] = *(const short8*)(Bg + boff[ni]);
            bu[ni] = *(const short8*)(Bu + boff[ni]);
        }
#pragma unroll
        for (int mi = 0; mi < 4; ++mi)
#pragma unroll
            for (int ni = 0; ni < 2; ++ni) {
                accG[mi][ni] = mfma16(a[mi], bg[ni], accG[mi][ni]);
                accU[mi][ni] = mfma16(a[mi], bu[ni], accU[mi][ni]);
            }
        __syncthreads();
    }

    const int obase = tn * 64 + wn * 32;
#pragma unroll
    for (int mi = 0; mi < 4; ++mi)
#pragma unroll
        for (int ni = 0; ni < 2; ++ni)
#pragma unroll
            for (int r = 0; r < 4; ++r) {
                int row = wm * 64 + mi * 16 + (lane >> 4) * 4 + r;
                int v = rowv[row];
                if (v < 0) continue;
                float g = accG[mi][ni][r], u = accU[mi][ni][r];
                float s = g / (1.f + expf(-g)) * u;
                act[(size_t)v * I_DIM + obase + ni * 16 + (lane & 15)] = f2bf(s);
            }
}

// ---------------- gemm2: out[t] += wts[v] * act[v].W2^T, bf16 MFMA ----------------
// block tile: M=128 (gathered act rows) x N=128 h-range; 4 waves, each 64x64.
template <bool BPRE>
__global__ __launch_bounds__(256)
void moe_mfma2(const u16* __restrict__ act, const void* __restrict__ w2v,
               const int* __restrict__ counts, const int* __restrict__ entries,
               const float* __restrict__ wts, float* __restrict__ out) {
    const int e  = blockIdx.z;
    const int ne = counts[e];
    const int tm = blockIdx.y;
    if (tm * 128 >= ne) return;
    const int tn = blockIdx.x;               // h-base = tn*128

    __shared__ __align__(16) u16 As[128 * 32];
    __shared__ __align__(16) u16 Bs[128 * 32];
    __shared__ int   rowv[128];
    __shared__ int   rowt[128];
    __shared__ float roww[128];

    const int tid = threadIdx.x;
    if (tid < 128) {
        int r = tm * 128 + tid;
        int v = (r < ne) ? entries[(size_t)e * T_TOK + r] : -1;
        rowv[tid] = v;
        rowt[tid] = (v < 0) ? 0 : (v >> 1);
        roww[tid] = (v < 0) ? 0.f : wts[v];
    }
    __syncthreads();

    const u16* asrc[2]; u16* adst[2];
    size_t bsrc[2]; u16* bdst[2];
    const u16*   w2b = (const u16*)w2v;
    const float* w2f = (const float*)w2v;
#pragma unroll
    for (int q = 0; q < 2; ++q) {
        int i = q * 256 + tid;
        int row = i >> 2, p = i & 3;
        int lc = p ^ swz(row);
        int v = rowv[row]; if (v < 0) v = 0;
        asrc[q] = act + (size_t)v * I_DIM + lc * 8;
        adst[q] = As + i * 8;
        bsrc[q] = ((size_t)e * H_DIM + tn * 128 + row) * I_DIM + lc * 8;
        bdst[q] = Bs + i * 8;
    }

    const int lane = tid & 63, wid = tid >> 6;
    const int wm = wid & 1, wn = wid >> 1;

    floatx4 acc[4][4];
    const floatx4 z4 = {0.f, 0.f, 0.f, 0.f};
#pragma unroll
    for (int mi = 0; mi < 4; ++mi)
#pragma unroll
        for (int ni = 0; ni < 4; ++ni) acc[mi][ni] = z4;

    int aoff[4], boff[4];
#pragma unroll
    for (int mi = 0; mi < 4; ++mi) {
        int m = wm * 64 + mi * 16 + (lane & 15);
        aoff[mi] = m * 32 + (((lane >> 4) ^ swz(m)) * 8);
    }
#pragma unroll
    for (int ni = 0; ni < 4; ++ni) {
        int n = wn * 64 + ni * 16 + (lane & 15);
        boff[ni] = n * 32 + (((lane >> 4) ^ swz(n)) * 8);
    }

    for (int k0 = 0; k0 < I_DIM; k0 += 32) {
        gload16(asrc[0] + k0, adst[0]);
        gload16(asrc[1] + k0, adst[1]);
        if (BPRE) {
            gload16(w2b + bsrc[0] + k0, bdst[0]);
            gload16(w2b + bsrc[1] + k0, bdst[1]);
        } else {
#pragma unroll
            for (int q = 0; q < 2; ++q) {
                const float* bs = w2f + bsrc[q] + k0;
                float4 b0 = *(const float4*)bs, b1 = *(const float4*)(bs + 4);
                ushort8 bv;
                bv[0] = f2bf(b0.x); bv[1] = f2bf(b0.y); bv[2] = f2bf(b0.z); bv[3] = f2bf(b0.w);
                bv[4] = f2bf(b1.x); bv[5] = f2bf(b1.y); bv[6] = f2bf(b1.z); bv[7] = f2bf(b1.w);
                *(ushort8*)bdst[q] = bv;
            }
        }
        __syncthreads();
        short8 a[4], b[4];
#pragma unroll
        for (int mi = 0; mi < 4; ++mi) a[mi] = *(const short8*)(As + aoff[mi]);
#pragma unroll
        for (int ni = 0; ni < 4; ++ni) b[ni] = *(const short8*)(Bs + boff[ni]);
#pragma unroll
        for (int mi = 0; mi < 4; ++mi)
#pragma unroll
            for (int ni = 0; ni < 4; ++ni)
                acc[mi][ni] = mfma16(a[mi], b[ni], acc[mi][ni]);
        __syncthreads();
    }

    const int hbase = tn * 128 + wn * 64;
#pragma unroll
    for (int mi = 0; mi < 4; ++mi)
#pragma unroll
        for (int ni = 0; ni < 4; ++ni)
#pragma unroll
            for (int r = 0; r < 4; ++r) {
                int row = wm * 64 + mi * 16 + (lane >> 4) * 4 + r;
                if (rowv[row] < 0) continue;
                atomicAdd(out + (size_t)rowt[row] * H_DIM + hbase + ni * 16 + (lane & 15),
                          roww[row] * acc[mi][ni][r]);
            }
}

extern "C" void kernel_launch(void* const* d_in, const int* in_sizes, int n_in,
                              void* d_out, int out_size, void* d_ws, size_t ws_size,
                              hipStream_t stream) {
    const float* x  = (const float*)d_in[0];   // [T, H]
    const float* gw = (const float*)d_in[1];   // [E, H]
    const float* w1 = (const float*)d_in[2];   // [E, 2I, H]
    const float* w2 = (const float*)d_in[3];   // [E, H, I]
    float* out = (float*)d_out;                // [T, H]

    char* ws = (char*)d_ws;
    int*   counts  = (int*)ws;                       // 256 B
    int*   entries = (int*)(ws + 256);               // 64 KB
    float* wts     = (float*)(ws + 256 + 65536);     // 16 KB
    u16* xb  = (u16*)(ws + 131072);                  // 8 MB
    u16* act = xb  + (size_t)T_TOK * H_DIM;          // 11 MB
    u16* w1b = act + (size_t)2 * T_TOK * I_DIM;      // 92 MB (optional)
    u16* w2b = w1b + (size_t)E_NUM * I2 * H_DIM;     // 46 MB (optional)
    const size_t need = 131072 + 2ull * ((size_t)T_TOK * H_DIM + 2ull * T_TOK * I_DIM +
                                         (size_t)E_NUM * I2 * H_DIM +
                                         (size_t)E_NUM * H_DIM * I_DIM);
    const bool pre = (ws_size >= need);

    hipMemsetAsync(counts, 0, 256, stream);
    hipMemsetAsync(out, 0, (size_t)T_TOK * H_DIM * sizeof(float), stream);

    moe_gating<<<T_TOK / 4, 256, 0, stream>>>(x, gw, wts, counts, entries);
    cvt_bf16<<<(T_TOK * H_DIM / 8 + 255) / 256, 256, 0, stream>>>(x, xb, T_TOK * H_DIM / 8);

    if (pre) {
        cvt_bf16<<<(E_NUM * I2 * H_DIM / 8 + 255) / 256, 256, 0, stream>>>(w1, w1b, E_NUM * I2 * H_DIM / 8);
        cvt_bf16<<<(E_NUM * H_DIM * I_DIM / 8 + 255) / 256, 256, 0, stream>>>(w2, w2b, E_NUM * H_DIM * I_DIM / 8);
        moe_mfma1<true><<<dim3(I_DIM / 64, 16, E_NUM), 256, 0, stream>>>(xb, w1b, counts, entries, act);
        moe_mfma2<true><<<dim3(H_DIM / 128, 16, E_NUM), 256, 0, stream>>>(act, w2b, counts, entries, wts, out);
    } else {
        moe_mfma1<false><<<dim3(I_DIM / 64, 16, E_NUM), 256, 0, stream>>>(xb, w1, counts, entries, act);
        moe_mfma2<false><<<dim3(H_DIM / 128, 16, E_NUM), 256, 0, stream>>>(act, w2, counts, entries, wts, out);
    }
}